// Round 2
// baseline (387.662 us; speedup 1.0000x reference)
//
#include <hip/hip_runtime.h>
#include <stdint.h>

typedef unsigned short u16;
typedef __attribute__((ext_vector_type(4))) float    floatx4;
typedef __attribute__((ext_vector_type(8))) __bf16   bf16x8;
typedef __attribute__((ext_vector_type(2))) unsigned int uintx2;
typedef __attribute__((ext_vector_type(4))) unsigned int uintx4;

__device__ inline u16 f2bf(float f) {            // RNE float->bf16
  unsigned int u = __builtin_bit_cast(unsigned int, f);
  u += 0x7fffu + ((u >> 16) & 1u);
  return (u16)(u >> 16);
}

#define GLD16(gsrc, ldst)                                                        \
  __builtin_amdgcn_global_load_lds(                                              \
      (__attribute__((address_space(1))) void*)(gsrc),                           \
      (__attribute__((address_space(3))) void*)(ldst), 16, 0, 0)

// ---------------------------------------------------------------------------
// combined prep: z<3 -> transpose-cast W_z into WT; z>=3 -> cast x -> bf16
__global__ __launch_bounds__(256) void prep_kernel(const float* __restrict__ x,
                                                   const float* __restrict__ Wq,
                                                   const float* __restrict__ Wk,
                                                   const float* __restrict__ Wv,
                                                   u16* __restrict__ xb,
                                                   u16* __restrict__ WT) {
  const int z = blockIdx.z;
  const int tid = threadIdx.y * 32 + threadIdx.x;
  if (z >= 3) {   // cast x chunk
    long blk = (long)(z - 3) * 1024 + blockIdx.y * 32 + blockIdx.x;
    long i = (blk * 256 + tid) * 8;
    floatx4 a = *(const floatx4*)(x + i);
    floatx4 b = *(const floatx4*)(x + i + 4);
    uintx4 o;
    o[0] = (unsigned)f2bf(a[0]) | ((unsigned)f2bf(a[1]) << 16);
    o[1] = (unsigned)f2bf(a[2]) | ((unsigned)f2bf(a[3]) << 16);
    o[2] = (unsigned)f2bf(b[0]) | ((unsigned)f2bf(b[1]) << 16);
    o[3] = (unsigned)f2bf(b[2]) | ((unsigned)f2bf(b[3]) << 16);
    *(uintx4*)(xb + i) = o;
    return;
  }
  __shared__ float tile[32][33];
  const float* W = (z == 0) ? Wq : (z == 1) ? Wk : Wv;
  u16* dst = WT + (long)z * 1024 * 1024;
  int bx = blockIdx.x * 32, by = blockIdx.y * 32;
  int tx = threadIdx.x, ty = threadIdx.y;                 // 32 x 8
  for (int i = 0; i < 32; i += 8)
    tile[ty + i][tx] = W[(long)(by + ty + i) * 1024 + bx + tx];
  __syncthreads();
  for (int i = 0; i < 32; i += 8)
    dst[(long)(bx + ty + i) * 1024 + by + tx] = f2bf(tile[tx][ty + i]);
}

// ---------------------------------------------------------------------------
// gemm_bt: C[m][n] = sum_k A[m][k] * Bt[n][k]   (A, Bt bf16, lda=ldb=K)
// 256x256 tile, BK=64, 512 threads = 8 waves (2M x 4N), per-wave 128x64.
// 4-phase-per-K-tile pipeline (8-phase/2-tile template):
//   phase = { 4-8 ds_read | 2 global_load_lds | counted vmcnt | lgkmcnt(0) |
//             barrier | setprio(1) 16 MFMA setprio(0) }
// Staging unit = 64-row band (full BK) = 1 GLD16/thread; 8 units/K-tile.
// Schedule (tile t): ph0: B0,B1(t+1)  ph1: B2,B3(t+1)  ph2: A1,A3(t+1)
//                    ph3: A0,A2(t+2) -> buf[t&1] (bands 0,2 dead after ph2).
// vmcnt(4) at ph0 & ph3 (derived: 4-10 loads in flight, never drained mid-loop).
// MFMA operands SWAPPED: acc = mfma(b_frag, a_frag).
// MODE 0: merged q|k projection; MODE 1: vT scatter; MODE 2: exp+rowsum;
// MODE 3: fp32 / lsum[row].
#define BM 256
#define BN 256
#define BK 64

template <int MODE, int GN>
__global__ __launch_bounds__(512, 2)
void gemm_bt(const u16* __restrict__ Aall, const u16* __restrict__ Ball,
             void* __restrict__ Call, void* __restrict__ C2,
             const float* __restrict__ bias, const float* __restrict__ bias2,
             float* __restrict__ lsum,
             int M, int N, int K, long aStride, long bStride, long cStride) {
  __shared__ __align__(16) u16 As[2][BM * BK];   // 2 x 32 KB
  __shared__ __align__(16) u16 Bs[2][BN * BK];   // 2 x 32 KB

  const int z = blockIdx.z;
  const u16* A  = Aall + (long)z * aStride;
  const u16* Bt = Ball + (long)z * bStride;

  int m_idx, n_idx;
  if (GN > 0) {
    const int tiles_n = gridDim.x, tiles_m = gridDim.y;
    int bid = blockIdx.y * tiles_n + blockIdx.x;
    int per_group = GN * tiles_m;
    int g = bid / per_group;
    int rem = bid - g * per_group;
    n_idx = g * GN + rem % GN;
    m_idx = rem / GN;
  } else {
    m_idx = blockIdx.y; n_idx = blockIdx.x;
  }

  const int tid  = threadIdx.x;
  const int m0   = m_idx * BM;
  const int n0   = n_idx * BN;
  const int wave = tid >> 6;
  const int lane = tid & 63;
  const int wm   = (wave >> 2) * 128;    // wave row offset (2 waves in M)
  const int wn   = (wave & 3) * 64;      // wave col offset (4 waves in N)
  const int l15  = lane & 15;
  const int quad = lane >> 4;

  floatx4 acc[8][4];
  floatx4 zero = {0.f, 0.f, 0.f, 0.f};
#pragma unroll
  for (int i = 0; i < 8; ++i)
#pragma unroll
    for (int j = 0; j < 4; ++j) acc[i][j] = zero;

  // staging: chunk ci = band*512+tid -> row r=ci>>3, slot sc=ci&7; LDS slot ci
  // holds source k-chunk sc^(r&7) (source-swizzled, linear LDS dest; rule #21).
  int rows[4], cols[4];
#pragma unroll
  for (int i = 0; i < 4; ++i) {
    int ci = i * 512 + tid;
    int r = ci >> 3, sc = ci & 7;
    rows[i] = r; cols[i] = (sc ^ (r & 7)) * 8;
  }

  auto stageA = [&](int kt2, u16* dst, int b) {
    GLD16(A + (long)(m0 + rows[b]) * K + kt2 + cols[b], dst + (b * 512 + tid) * 8);
  };
  auto stageB = [&](int kt2, u16* dst, int b) {
    GLD16(Bt + (long)(n0 + rows[b]) * K + kt2 + cols[b], dst + (b * 512 + tid) * 8);
  };

  const int nt = K / BK;            // 16 or 32 here (always >= 2, even)

  // prologue: tile0 all 8 units + tile1 A0,A2  (virtual ph3(-2)..ph3(-1) order)
  stageA(0, As[0], 0); stageA(0, As[0], 2);
  stageB(0, Bs[0], 0); stageB(0, Bs[0], 1);
  stageB(0, Bs[0], 2); stageB(0, Bs[0], 3);
  stageA(0, As[0], 1); stageA(0, As[0], 3);
  stageA(BK, As[1], 0); stageA(BK, As[1], 2);
  asm volatile("s_waitcnt vmcnt(2)" ::: "memory");   // tile0 fully landed
  __builtin_amdgcn_sched_barrier(0);
  __builtin_amdgcn_s_barrier();
  __builtin_amdgcn_sched_barrier(0);

  for (int t = 0; t < nt; ++t) {
    const int cur = t & 1;
    const u16* Ab = As[cur];
    const u16* Bb = Bs[cur];
    u16* Ac = As[cur];                 // ph3 stages tile t+2 into cur buffer
    u16* An = As[cur ^ 1];
    u16* Bn = Bs[cur ^ 1];
    const int ktn = (t + 1) * BK;
    const bool st1 = (t + 1 < nt);
    const bool st2 = (t + 2 < nt);
    bf16x8 afA[4], afB[4], bfr[4];

    // ================= phase 0: ks0, mi 0-3 =================
#pragma unroll
    for (int mi = 0; mi < 4; ++mi) {
      int r = wm + mi * 16 + l15;
      afA[mi] = *(const bf16x8*)(Ab + (r * 8 + (quad ^ (r & 7))) * 8);
    }
#pragma unroll
    for (int ni = 0; ni < 4; ++ni) {
      int r = wn + ni * 16 + l15;
      bfr[ni] = *(const bf16x8*)(Bb + (r * 8 + (quad ^ (r & 7))) * 8);
    }
    if (st1) { stageB(ktn, Bn, 0); stageB(ktn, Bn, 1); }
    if (st1) asm volatile("s_waitcnt vmcnt(4)" ::: "memory");
    else     asm volatile("s_waitcnt vmcnt(0)" ::: "memory");
    asm volatile("s_waitcnt lgkmcnt(0)" ::: "memory");
    __builtin_amdgcn_sched_barrier(0);
    __builtin_amdgcn_s_barrier();
    __builtin_amdgcn_sched_barrier(0);
    __builtin_amdgcn_s_setprio(1);
#pragma unroll
    for (int mi = 0; mi < 4; ++mi)
#pragma unroll
      for (int ni = 0; ni < 4; ++ni)
        acc[mi][ni] = __builtin_amdgcn_mfma_f32_16x16x32_bf16(
            bfr[ni], afA[mi], acc[mi][ni], 0, 0, 0);
    __builtin_amdgcn_s_setprio(0);
    __builtin_amdgcn_sched_barrier(0);

    // ================= phase 1: ks0, mi 4-7 =================
#pragma unroll
    for (int mi = 0; mi < 4; ++mi) {
      int r = wm + (4 + mi) * 16 + l15;
      afB[mi] = *(const bf16x8*)(Ab + (r * 8 + (quad ^ (r & 7))) * 8);
    }
    if (st1) { stageB(ktn, Bn, 2); stageB(ktn, Bn, 3); }
    asm volatile("s_waitcnt lgkmcnt(0)" ::: "memory");
    __builtin_amdgcn_sched_barrier(0);
    __builtin_amdgcn_s_barrier();
    __builtin_amdgcn_sched_barrier(0);
    __builtin_amdgcn_s_setprio(1);
#pragma unroll
    for (int mi = 0; mi < 4; ++mi)
#pragma unroll
      for (int ni = 0; ni < 4; ++ni)
        acc[4 + mi][ni] = __builtin_amdgcn_mfma_f32_16x16x32_bf16(
            bfr[ni], afB[mi], acc[4 + mi][ni], 0, 0, 0);
    __builtin_amdgcn_s_setprio(0);
    __builtin_amdgcn_sched_barrier(0);

    // ================= phase 2: ks1, mi 0-3 =================
#pragma unroll
    for (int mi = 0; mi < 4; ++mi) {
      int r = wm + mi * 16 + l15;
      afA[mi] = *(const bf16x8*)(Ab + (r * 8 + ((4 + quad) ^ (r & 7))) * 8);
    }
#pragma unroll
    for (int ni = 0; ni < 4; ++ni) {
      int r = wn + ni * 16 + l15;
      bfr[ni] = *(const bf16x8*)(Bb + (r * 8 + ((4 + quad) ^ (r & 7))) * 8);
    }
    if (st1) { stageA(ktn, An, 1); stageA(ktn, An, 3); }
    asm volatile("s_waitcnt lgkmcnt(0)" ::: "memory");
    __builtin_amdgcn_sched_barrier(0);
    __builtin_amdgcn_s_barrier();
    __builtin_amdgcn_sched_barrier(0);
    __builtin_amdgcn_s_setprio(1);
#pragma unroll
    for (int mi = 0; mi < 4; ++mi)
#pragma unroll
      for (int ni = 0; ni < 4; ++ni)
        acc[mi][ni] = __builtin_amdgcn_mfma_f32_16x16x32_bf16(
            bfr[ni], afA[mi], acc[mi][ni], 0, 0, 0);
    __builtin_amdgcn_s_setprio(0);
    __builtin_amdgcn_sched_barrier(0);

    // ================= phase 3: ks1, mi 4-7 =================
#pragma unroll
    for (int mi = 0; mi < 4; ++mi) {
      int r = wm + (4 + mi) * 16 + l15;
      afB[mi] = *(const bf16x8*)(Ab + (r * 8 + ((4 + quad) ^ (r & 7))) * 8);
    }
    if (st2) { stageA(ktn + BK, Ac, 0); stageA(ktn + BK, Ac, 2); }
    if (st2)      asm volatile("s_waitcnt vmcnt(4)" ::: "memory");
    else if (st1) asm volatile("s_waitcnt vmcnt(2)" ::: "memory");
    asm volatile("s_waitcnt lgkmcnt(0)" ::: "memory");
    __builtin_amdgcn_sched_barrier(0);
    __builtin_amdgcn_s_barrier();
    __builtin_amdgcn_sched_barrier(0);
    __builtin_amdgcn_s_setprio(1);
#pragma unroll
    for (int mi = 0; mi < 4; ++mi)
#pragma unroll
      for (int ni = 0; ni < 4; ++ni)
        acc[4 + mi][ni] = __builtin_amdgcn_mfma_f32_16x16x32_bf16(
            bfr[ni], afB[mi], acc[4 + mi][ni], 0, 0, 0);
    __builtin_amdgcn_s_setprio(0);
    __builtin_amdgcn_sched_barrier(0);
  }

  // epilogue (swapped D layout): row(m) = l15-based, 4 regs = 4 consecutive n-cols
#pragma unroll
  for (int mi = 0; mi < 8; ++mi) {
    const int row = m0 + wm + mi * 16 + l15;      // fixed per lane
    if (MODE == 2) {
      u16* C = (u16*)Call + (long)z * cStride;
      float rs = 0.f;
#pragma unroll
      for (int ni = 0; ni < 4; ++ni) {
        int colb = n0 + wn + ni * 16 + quad * 4;
        floatx4 v = acc[mi][ni];
        float e0 = __expf(v[0] * 0.03125f), e1 = __expf(v[1] * 0.03125f);
        float e2 = __expf(v[2] * 0.03125f), e3 = __expf(v[3] * 0.03125f);
        rs += (e0 + e1) + (e2 + e3);
        uintx2 o;
        o[0] = (unsigned)f2bf(e0) | ((unsigned)f2bf(e1) << 16);
        o[1] = (unsigned)f2bf(e2) | ((unsigned)f2bf(e3) << 16);
        *(uintx2*)(C + (long)row * N + colb) = o;
      }
      rs += __shfl_xor(rs, 16);
      rs += __shfl_xor(rs, 32);
      if (quad == 0) atomicAdd(lsum + (long)z * 2048 + row, rs);
    } else if (MODE == 3) {
      float* C = (float*)Call + (long)z * cStride;
      float inv = 1.0f / lsum[(long)z * 2048 + row];
#pragma unroll
      for (int ni = 0; ni < 4; ++ni) {
        int colb = n0 + wn + ni * 16 + quad * 4;
        floatx4 v = acc[mi][ni];
        floatx4 o = {v[0] * inv, v[1] * inv, v[2] * inv, v[3] * inv};
        *(floatx4*)(C + (long)row * N + colb) = o;
      }
    } else if (MODE == 0) {
#pragma unroll
      for (int ni = 0; ni < 4; ++ni) {
        int colb = n0 + wn + ni * 16 + quad * 4;
        u16* C = (colb < 1024) ? (u16*)Call : (u16*)C2;
        const float* bp = (colb < 1024) ? bias + colb : bias2 + (colb - 1024);
        floatx4 b = *(const floatx4*)bp;
        floatx4 v = acc[mi][ni];
        uintx2 o;
        o[0] = (unsigned)f2bf(v[0] + b[0]) | ((unsigned)f2bf(v[1] + b[1]) << 16);
        o[1] = (unsigned)f2bf(v[2] + b[2]) | ((unsigned)f2bf(v[3] + b[3]) << 16);
        *(uintx2*)(C + (long)row * 1024 + (colb & 1023)) = o;
      }
    } else {  // MODE 1: vT scatter — row=do, cols=4 consecutive t
      u16* C = (u16*)Call;
      float b = bias[row];
#pragma unroll
      for (int ni = 0; ni < 4; ++ni) {
        int colb = n0 + wn + ni * 16 + quad * 4;   // global t index over B*T
        long base = ((long)(colb >> 11) * 1024) * 2048 + (colb & 2047);
        floatx4 v = acc[mi][ni];
        uintx2 o;
        o[0] = (unsigned)f2bf(v[0] + b) | ((unsigned)f2bf(v[1] + b) << 16);
        o[1] = (unsigned)f2bf(v[2] + b) | ((unsigned)f2bf(v[3] + b) << 16);
        *(uintx2*)(C + base + (long)row * 2048) = o;
      }
    }
  }
}

// ---------------------------------------------------------------------------
extern "C" void kernel_launch(void* const* d_in, const int* in_sizes, int n_in,
                              void* d_out, int out_size, void* d_ws, size_t ws_size,
                              hipStream_t stream) {
  const float* x  = (const float*)d_in[0];
  const float* Wq = (const float*)d_in[1];
  const float* bq = (const float*)d_in[2];
  const float* Wk = (const float*)d_in[3];
  const float* bk = (const float*)d_in[4];
  const float* Wv = (const float*)d_in[5];
  const float* bv = (const float*)d_in[6];
  float* out = (float*)d_out;

  const long BT = 16384;   // B*T
  u16* xb = (u16*)d_ws;                    // [16384,1024] bf16   32 MB
  u16* WT = xb + BT * 1024;                // [3][1024,1024]       6 MB
  u16* qb = WT + 3L * 1024 * 1024;         // [16384,1024]        32 MB
  u16* kb = qb + BT * 1024;                // [16384,1024]        32 MB
  u16* vT = kb + BT * 1024;                // [8][1024][2048]     32 MB
  u16* S  = vT + BT * 1024;                // [8][2048][2048]     64 MB
  float* lsum = (float*)(S + 8L * 2048 * 2048);   // [8][2048]    64 KB

  hipMemsetAsync(lsum, 0, 8 * 2048 * sizeof(float), stream);

  // z 0..2: transpose-cast W; z 3..10: cast x
  prep_kernel<<<dim3(32, 32, 11), dim3(32, 8), 0, stream>>>(x, Wq, Wk, Wv, xb, WT);

  // q|k = x [Wq|Wk] + [bq|bk]   (WT rows 0..2047 are Wq^T then Wk^T)
  gemm_bt<0, 8><<<dim3(8, 64, 1), 512, 0, stream>>>(
      xb, WT, qb, kb, bq, bk, nullptr, 16384, 2048, 1024, 0, 0, 0);
  // vT[b][do][t] = (Wv^T x^T + bv) : A=WvT [1024,1024], Bt=xb [16384,1024]
  gemm_bt<1, 8><<<dim3(64, 4, 1), 512, 0, stream>>>(
      WT + 2L * 1024 * 1024, xb, vT, nullptr, bv, nullptr, nullptr,
      1024, 16384, 1024, 0, 0, 0);
  // E[b] = exp(q_b k_b^T / 32), row-sums -> lsum
  gemm_bt<2, 8><<<dim3(8, 8, 8), 512, 0, stream>>>(
      qb, kb, S, nullptr, nullptr, nullptr, lsum,
      2048, 2048, 1024, 2048L * 1024, 2048L * 1024, 2048L * 2048);
  // out[b] = (E_b V_b) / lsum : A=E [2048,2048], Bt=vT_b [1024,2048]
  gemm_bt<3, 4><<<dim3(4, 8, 8), 512, 0, stream>>>(
      S, vT, out, nullptr, nullptr, nullptr, lsum,
      2048, 1024, 2048, 2048L * 2048, 1024L * 2048, 2048L * 1024);
}

// Round 4
// 381.112 us; speedup vs baseline: 1.0172x; 1.0172x over previous
//
#include <hip/hip_runtime.h>
#include <stdint.h>

typedef unsigned short u16;
typedef __attribute__((ext_vector_type(4))) float    floatx4;
typedef __attribute__((ext_vector_type(8))) __bf16   bf16x8;
typedef __attribute__((ext_vector_type(2))) unsigned int uintx2;
typedef __attribute__((ext_vector_type(4))) unsigned int uintx4;

__device__ inline u16 f2bf(float f) {            // RNE float->bf16
  unsigned int u = __builtin_bit_cast(unsigned int, f);
  u += 0x7fffu + ((u >> 16) & 1u);
  return (u16)(u >> 16);
}

#define GLD16(gsrc, ldst)                                                        \
  __builtin_amdgcn_global_load_lds(                                              \
      (__attribute__((address_space(1))) void*)(gsrc),                           \
      (__attribute__((address_space(3))) void*)(ldst), 16, 0, 0)

#define SB() __builtin_amdgcn_sched_barrier(0)

// ---------------------------------------------------------------------------
// combined prep: z<3 -> transpose-cast W_z into WT; z>=3 -> cast x -> bf16
__global__ __launch_bounds__(256) void prep_kernel(const float* __restrict__ x,
                                                   const float* __restrict__ Wq,
                                                   const float* __restrict__ Wk,
                                                   const float* __restrict__ Wv,
                                                   u16* __restrict__ xb,
                                                   u16* __restrict__ WT) {
  const int z = blockIdx.z;
  const int tid = threadIdx.y * 32 + threadIdx.x;
  if (z >= 3) {   // cast x chunk
    long blk = (long)(z - 3) * 1024 + blockIdx.y * 32 + blockIdx.x;
    long i = (blk * 256 + tid) * 8;
    floatx4 a = *(const floatx4*)(x + i);
    floatx4 b = *(const floatx4*)(x + i + 4);
    uintx4 o;
    o[0] = (unsigned)f2bf(a[0]) | ((unsigned)f2bf(a[1]) << 16);
    o[1] = (unsigned)f2bf(a[2]) | ((unsigned)f2bf(a[3]) << 16);
    o[2] = (unsigned)f2bf(b[0]) | ((unsigned)f2bf(b[1]) << 16);
    o[3] = (unsigned)f2bf(b[2]) | ((unsigned)f2bf(b[3]) << 16);
    *(uintx4*)(xb + i) = o;
    return;
  }
  __shared__ float tile[32][33];
  const float* W = (z == 0) ? Wq : (z == 1) ? Wk : Wv;
  u16* dst = WT + (long)z * 1024 * 1024;
  int bx = blockIdx.x * 32, by = blockIdx.y * 32;
  int tx = threadIdx.x, ty = threadIdx.y;                 // 32 x 8
  for (int i = 0; i < 32; i += 8)
    tile[ty + i][tx] = W[(long)(by + ty + i) * 1024 + bx + tx];
  __syncthreads();
  for (int i = 0; i < 32; i += 8)
    dst[(long)(bx + ty + i) * 1024 + by + tx] = f2bf(tile[tx][ty + i]);
}

// ---------------------------------------------------------------------------
// gemm_bt: C[m][n] = sum_k A[m][k] * Bt[n][k]   (A, Bt bf16, lda=ldb=K)
// 256x256 tile, BK=64, 512 threads = 8 waves (2M x 4N), per-wave 128x64.
// 4 phases per K-tile; lgkmcnt(0) AFTER the barrier (template-faithful):
// waves enter the barrier with ds_reads in flight so read latency overlaps
// barrier convergence. vmcnt stays pre-barrier (cross-wave DMA visibility).
// Stage schedule (tile t, all -> next buffer): ph0:B01(t+1) ph1:B23(t+1)
// ph2:A02(t+1) ph3:A13(t+1).  Waits: vmcnt(2) at ph0 & ph3 only.
// Visibility ledger: ph3(t-1) vmcnt(2) forces B01,B23,A02(t) pre-barrier ->
// visible to ph0(t) reads; ph0(t) vmcnt(2) forces A13(t) -> visible to ph1(t).
// PROLOGUE (r3 bugfix): tile 0's 8 DMAs must be vmcnt(0)-drained + barrier
// BEFORE the loop — ph0's ds_reads execute before any in-loop wait.
// Overwrite safety: stages target the opposite buffer, whose last reads
// drained (post-barrier lgkm) >= 1 full barrier before the stage issue.
// XCD swizzle: chunked bijective (all grids %8==0): L=(bid&7)*(nwg/8)+bid>>3.
// MODE 0: merged q|k projection; MODE 1: vT scatter; MODE 2: exp+rowsum;
// MODE 3: fp32 / lsum[row].
#define BM 256
#define BN 256
#define BK 64

template <int MODE, int GN>
__global__ __launch_bounds__(512, 2)
void gemm_bt(const u16* __restrict__ Aall, const u16* __restrict__ Ball,
             void* __restrict__ Call, void* __restrict__ C2,
             const float* __restrict__ bias, const float* __restrict__ bias2,
             float* __restrict__ lsum,
             int M, int N, int K, long aStride, long bStride, long cStride) {
  __shared__ __align__(16) u16 As[2][BM * BK];   // 2 x 32 KB
  __shared__ __align__(16) u16 Bs[2][BN * BK];   // 2 x 32 KB

  const int z = blockIdx.z;
  const u16* A  = Aall + (long)z * aStride;
  const u16* Bt = Ball + (long)z * bStride;

  // XCD-chunked bijective swizzle, then GN grouping
  int m_idx, n_idx;
  {
    const int tiles_n = gridDim.x, tiles_m = gridDim.y;
    int nwg = tiles_n * tiles_m;
    int bid = blockIdx.y * tiles_n + blockIdx.x;
    int qq = nwg >> 3;                       // all grids are %8 == 0
    int L = (bid & 7) * qq + (bid >> 3);
    int per_group = GN * tiles_m;
    int g = L / per_group;
    int rem = L - g * per_group;
    n_idx = g * GN + rem % GN;
    m_idx = rem / GN;
  }

  const int tid  = threadIdx.x;
  const int m0   = m_idx * BM;
  const int n0   = n_idx * BN;
  const int wave = tid >> 6;
  const int lane = tid & 63;
  const int wm   = (wave >> 2) * 128;    // wave row offset (2 waves in M)
  const int wn   = (wave & 3) * 64;      // wave col offset (4 waves in N)
  const int l15  = lane & 15;
  const int quad = lane >> 4;

  floatx4 acc[8][4];
  floatx4 zero = {0.f, 0.f, 0.f, 0.f};
#pragma unroll
  for (int i = 0; i < 8; ++i)
#pragma unroll
    for (int j = 0; j < 4; ++j) acc[i][j] = zero;

  // staging: chunk ci = band*512+tid -> row r=ci>>3, slot sc=ci&7; LDS slot ci
  // holds source k-chunk sc^(r&7) (source-swizzled, linear LDS dest; rule #21).
  int rows[4], cols[4];
#pragma unroll
  for (int i = 0; i < 4; ++i) {
    int ci = i * 512 + tid;
    int r = ci >> 3, sc = ci & 7;
    rows[i] = r; cols[i] = (sc ^ (r & 7)) * 8;
  }

  auto stageA = [&](int kt2, u16* dst, int b) {
    GLD16(A + (long)(m0 + rows[b]) * K + kt2 + cols[b], dst + (b * 512 + tid) * 8);
  };
  auto stageB = [&](int kt2, u16* dst, int b) {
    GLD16(Bt + (long)(n0 + rows[b]) * K + kt2 + cols[b], dst + (b * 512 + tid) * 8);
  };

  const int nt = K / BK;            // 16 or 32 here

  // prologue: all 8 units of tile 0, then FULL drain + barrier (r3 bugfix:
  // ph0's ds_reads of tile 0 run before any in-loop vmcnt).
  stageB(0, Bs[0], 0); stageB(0, Bs[0], 1);
  stageB(0, Bs[0], 2); stageB(0, Bs[0], 3);
  stageA(0, As[0], 0); stageA(0, As[0], 2);
  stageA(0, As[0], 1); stageA(0, As[0], 3);
  SB();
  asm volatile("s_waitcnt vmcnt(0)" ::: "memory");
  SB();
  __builtin_amdgcn_s_barrier();
  SB();

  for (int t = 0; t < nt; ++t) {
    const int cur = t & 1;
    const u16* Ab = As[cur];
    const u16* Bb = Bs[cur];
    u16* An = As[cur ^ 1];
    u16* Bn = Bs[cur ^ 1];
    const int ktn = (t + 1) * BK;
    const bool st1 = (t + 1 < nt);
    bf16x8 afA[4], afB[4], bfr[4];

    // ================= phase 0: ks0, mi 0-3 =================
#pragma unroll
    for (int mi = 0; mi < 4; ++mi) {
      int r = wm + mi * 16 + l15;
      afA[mi] = *(const bf16x8*)(Ab + (r * 8 + (quad ^ (r & 7))) * 8);
    }
#pragma unroll
    for (int ni = 0; ni < 4; ++ni) {
      int r = wn + ni * 16 + l15;
      bfr[ni] = *(const bf16x8*)(Bb + (r * 8 + (quad ^ (r & 7))) * 8);
    }
    if (st1) { stageB(ktn, Bn, 0); stageB(ktn, Bn, 1); }
    SB();
    if (st1) asm volatile("s_waitcnt vmcnt(2)" ::: "memory");
    else     asm volatile("s_waitcnt vmcnt(0)" ::: "memory");
    SB();
    __builtin_amdgcn_s_barrier();
    asm volatile("s_waitcnt lgkmcnt(0)" ::: "memory");
    SB();
    __builtin_amdgcn_s_setprio(1);
#pragma unroll
    for (int mi = 0; mi < 4; ++mi)
#pragma unroll
      for (int ni = 0; ni < 4; ++ni)
        acc[mi][ni] = __builtin_amdgcn_mfma_f32_16x16x32_bf16(
            bfr[ni], afA[mi], acc[mi][ni], 0, 0, 0);   // swapped operands
    __builtin_amdgcn_s_setprio(0);
    SB();

    // ================= phase 1: ks0, mi 4-7 =================
#pragma unroll
    for (int mi = 0; mi < 4; ++mi) {
      int r = wm + (4 + mi) * 16 + l15;
      afB[mi] = *(const bf16x8*)(Ab + (r * 8 + (quad ^ (r & 7))) * 8);
    }
    if (st1) { stageB(ktn, Bn, 2); stageB(ktn, Bn, 3); }
    SB();
    __builtin_amdgcn_s_barrier();
    asm volatile("s_waitcnt lgkmcnt(0)" ::: "memory");
    SB();
    __builtin_amdgcn_s_setprio(1);
#pragma unroll
    for (int mi = 0; mi < 4; ++mi)
#pragma unroll
      for (int ni = 0; ni < 4; ++ni)
        acc[4 + mi][ni] = __builtin_amdgcn_mfma_f32_16x16x32_bf16(
            bfr[ni], afB[mi], acc[4 + mi][ni], 0, 0, 0);
    __builtin_amdgcn_s_setprio(0);
    SB();

    // ================= phase 2: ks1, mi 0-3 =================
#pragma unroll
    for (int mi = 0; mi < 4; ++mi) {
      int r = wm + mi * 16 + l15;
      afA[mi] = *(const bf16x8*)(Ab + (r * 8 + ((4 + quad) ^ (r & 7))) * 8);
    }
#pragma unroll
    for (int ni = 0; ni < 4; ++ni) {
      int r = wn + ni * 16 + l15;
      bfr[ni] = *(const bf16x8*)(Bb + (r * 8 + ((4 + quad) ^ (r & 7))) * 8);
    }
    if (st1) { stageA(ktn, An, 0); stageA(ktn, An, 2); }
    SB();
    __builtin_amdgcn_s_barrier();
    asm volatile("s_waitcnt lgkmcnt(0)" ::: "memory");
    SB();
    __builtin_amdgcn_s_setprio(1);
#pragma unroll
    for (int mi = 0; mi < 4; ++mi)
#pragma unroll
      for (int ni = 0; ni < 4; ++ni)
        acc[mi][ni] = __builtin_amdgcn_mfma_f32_16x16x32_bf16(
            bfr[ni], afA[mi], acc[mi][ni], 0, 0, 0);
    __builtin_amdgcn_s_setprio(0);
    SB();

    // ================= phase 3: ks1, mi 4-7 =================
#pragma unroll
    for (int mi = 0; mi < 4; ++mi) {
      int r = wm + (4 + mi) * 16 + l15;
      afB[mi] = *(const bf16x8*)(Ab + (r * 8 + ((4 + quad) ^ (r & 7))) * 8);
    }
    if (st1) { stageA(ktn, An, 1); stageA(ktn, An, 3); }
    SB();
    if (st1) asm volatile("s_waitcnt vmcnt(2)" ::: "memory");
    SB();
    __builtin_amdgcn_s_barrier();
    asm volatile("s_waitcnt lgkmcnt(0)" ::: "memory");
    SB();
    __builtin_amdgcn_s_setprio(1);
#pragma unroll
    for (int mi = 0; mi < 4; ++mi)
#pragma unroll
      for (int ni = 0; ni < 4; ++ni)
        acc[4 + mi][ni] = __builtin_amdgcn_mfma_f32_16x16x32_bf16(
            bfr[ni], afB[mi], acc[4 + mi][ni], 0, 0, 0);
    __builtin_amdgcn_s_setprio(0);
    SB();
  }

  // epilogue (swapped D layout): row(m) = l15-based, 4 regs = 4 consecutive n-cols
#pragma unroll
  for (int mi = 0; mi < 8; ++mi) {
    const int row = m0 + wm + mi * 16 + l15;      // fixed per lane
    if (MODE == 2) {
      u16* C = (u16*)Call + (long)z * cStride;
      float rs = 0.f;
#pragma unroll
      for (int ni = 0; ni < 4; ++ni) {
        int colb = n0 + wn + ni * 16 + quad * 4;
        floatx4 v = acc[mi][ni];
        float e0 = __expf(v[0] * 0.03125f), e1 = __expf(v[1] * 0.03125f);
        float e2 = __expf(v[2] * 0.03125f), e3 = __expf(v[3] * 0.03125f);
        rs += (e0 + e1) + (e2 + e3);
        uintx2 o;
        o[0] = (unsigned)f2bf(e0) | ((unsigned)f2bf(e1) << 16);
        o[1] = (unsigned)f2bf(e2) | ((unsigned)f2bf(e3) << 16);
        *(uintx2*)(C + (long)row * N + colb) = o;
      }
      rs += __shfl_xor(rs, 16);
      rs += __shfl_xor(rs, 32);
      if (quad == 0) atomicAdd(lsum + (long)z * 2048 + row, rs);
    } else if (MODE == 3) {
      float* C = (float*)Call + (long)z * cStride;
      float inv = 1.0f / lsum[(long)z * 2048 + row];
#pragma unroll
      for (int ni = 0; ni < 4; ++ni) {
        int colb = n0 + wn + ni * 16 + quad * 4;
        floatx4 v = acc[mi][ni];
        floatx4 o = {v[0] * inv, v[1] * inv, v[2] * inv, v[3] * inv};
        *(floatx4*)(C + (long)row * N + colb) = o;
      }
    } else if (MODE == 0) {
#pragma unroll
      for (int ni = 0; ni < 4; ++ni) {
        int colb = n0 + wn + ni * 16 + quad * 4;
        u16* C = (colb < 1024) ? (u16*)Call : (u16*)C2;
        const float* bp = (colb < 1024) ? bias + colb : bias2 + (colb - 1024);
        floatx4 b = *(const floatx4*)bp;
        floatx4 v = acc[mi][ni];
        uintx2 o;
        o[0] = (unsigned)f2bf(v[0] + b[0]) | ((unsigned)f2bf(v[1] + b[1]) << 16);
        o[1] = (unsigned)f2bf(v[2] + b[2]) | ((unsigned)f2bf(v[3] + b[3]) << 16);
        *(uintx2*)(C + (long)row * 1024 + (colb & 1023)) = o;
      }
    } else {  // MODE 1: vT scatter — row=do, cols=4 consecutive t
      u16* C = (u16*)Call;
      float b = bias[row];
#pragma unroll
      for (int ni = 0; ni < 4; ++ni) {
        int colb = n0 + wn + ni * 16 + quad * 4;   // global t index over B*T
        long base = ((long)(colb >> 11) * 1024) * 2048 + (colb & 2047);
        floatx4 v = acc[mi][ni];
        uintx2 o;
        o[0] = (unsigned)f2bf(v[0] + b) | ((unsigned)f2bf(v[1] + b) << 16);
        o[1] = (unsigned)f2bf(v[2] + b) | ((unsigned)f2bf(v[3] + b) << 16);
        *(uintx2*)(C + base + (long)row * 2048) = o;
      }
    }
  }
}

// ---------------------------------------------------------------------------
extern "C" void kernel_launch(void* const* d_in, const int* in_sizes, int n_in,
                              void* d_out, int out_size, void* d_ws, size_t ws_size,
                              hipStream_t stream) {
  const float* x  = (const float*)d_in[0];
  const float* Wq = (const float*)d_in[1];
  const float* bq = (const float*)d_in[2];
  const float* Wk = (const float*)d_in[3];
  const float* bk = (const float*)d_in[4];
  const float* Wv = (const float*)d_in[5];
  const float* bv = (const float*)d_in[6];
  float* out = (float*)d_out;

  const long BT = 16384;   // B*T
  u16* xb = (u16*)d_ws;                    // [16384,1024] bf16   32 MB
  u16* WT = xb + BT * 1024;                // [3][1024,1024]       6 MB
  u16* qb = WT + 3L * 1024 * 1024;         // [16384,1024]        32 MB
  u16* kb = qb + BT * 1024;                // [16384,1024]        32 MB
  u16* vT = kb + BT * 1024;                // [8][1024][2048]     32 MB
  u16* S  = vT + BT * 1024;                // [8][2048][2048]     64 MB
  float* lsum = (float*)(S + 8L * 2048 * 2048);   // [8][2048]    64 KB

  hipMemsetAsync(lsum, 0, 8 * 2048 * sizeof(float), stream);

  // z 0..2: transpose-cast W; z 3..10: cast x
  prep_kernel<<<dim3(32, 32, 11), dim3(32, 8), 0, stream>>>(x, Wq, Wk, Wv, xb, WT);

  // q|k = x [Wq|Wk] + [bq|bk]   (WT rows 0..2047 are Wq^T then Wk^T)
  gemm_bt<0, 8><<<dim3(8, 64, 1), 512, 0, stream>>>(
      xb, WT, qb, kb, bq, bk, nullptr, 16384, 2048, 1024, 0, 0, 0);
  // vT[b][do][t] = (Wv^T x^T + bv) : A=WvT [1024,1024], Bt=xb [16384,1024]
  gemm_bt<1, 8><<<dim3(64, 4, 1), 512, 0, stream>>>(
      WT + 2L * 1024 * 1024, xb, vT, nullptr, bv, nullptr, nullptr,
      1024, 16384, 1024, 0, 0, 0);
  // E[b] = exp(q_b k_b^T / 32), row-sums -> lsum
  gemm_bt<2, 8><<<dim3(8, 8, 8), 512, 0, stream>>>(
      qb, kb, S, nullptr, nullptr, nullptr, lsum,
      2048, 2048, 1024, 2048L * 1024, 2048L * 1024, 2048L * 2048);
  // out[b] = (E_b V_b) / lsum : A=E [2048,2048], Bt=vT_b [1024,2048]
  gemm_bt<3, 4><<<dim3(4, 8, 8), 512, 0, stream>>>(
      S, vT, out, nullptr, nullptr, nullptr, lsum,
      2048, 1024, 2048, 2048L * 2048, 1024L * 2048, 2048L * 1024);
}